// Round 2
// baseline (145.590 us; speedup 1.0000x reference)
//
#include <hip/hip_runtime.h>
#include <hip/hip_bf16.h>
#include <stdint.h>

#define BB 8
#define LL 2048
#define DD 64

typedef short bf16x8 __attribute__((ext_vector_type(8)));  // 8 bf16 bit patterns (4 VGPRs)
typedef float f32x4 __attribute__((ext_vector_type(4)));

// round-half-up float -> bf16 bits (inputs finite; err <= 0.5 ulp)
__device__ __forceinline__ unsigned f2bf_u(float f) {
    union { float f; unsigned u; } v; v.f = f;
    return (v.u + 0x8000u) >> 16;
}

// convert 8 contiguous fp32 -> bf16x8 A/B fragment (two float4 loads)
__device__ __forceinline__ bf16x8 cvt8(const float* __restrict__ p) {
    float4 a = *reinterpret_cast<const float4*>(p);
    float4 b = *reinterpret_cast<const float4*>(p + 4);
    union { bf16x8 v; unsigned u[4]; } r;
    r.u[0] = f2bf_u(a.x) | (f2bf_u(a.y) << 16);
    r.u[1] = f2bf_u(a.z) | (f2bf_u(a.w) << 16);
    r.u[2] = f2bf_u(b.x) | (f2bf_u(b.y) << 16);
    r.u[3] = f2bf_u(b.z) | (f2bf_u(b.w) << 16);
    return r.v;
}

// Layouts (gfx950, HW-verified per guide):
//   mfma_f32_16x16x32_bf16 A-frag: m=lane&15, k=(lane>>4)*8+j  (8 contiguous/lane)
//   B-frag: n=lane&15, k=(lane>>4)*8+j
//   C/D:    col=lane&15, row=(lane>>4)*4+reg
__global__ __launch_bounds__(256, 4) void attn_mfma(
    const float* __restrict__ Q,
    const float* __restrict__ K,
    const float* __restrict__ V,
    const int* __restrict__ qmask,
    const int* __restrict__ kmask,
    float* __restrict__ Out)
{
    const int tid  = threadIdx.x;
    const int wave = tid >> 6;        // k-split index 0..3
    const int lane = tid & 63;
    const int n    = lane & 15;
    const int quad = lane >> 4;

    const int bx = blockIdx.x;
    const int b  = bx >> 7;           // 8 batches
    const int q0 = (bx & 127) << 4;   // 16 queries per block

    // P buffer in A-frag-linear order, stride 9 dwords per 8-float group:
    // element (q, k_local) -> dword 9*((k_local>>3)*16 + q) + (k_local&7).
    // Both the 8 scatter-writes and 8 reads are <=2-way bank conflicts (free).
    __shared__ float Pl[4][576];
    __shared__ float Opart[4][16][68]; // stride 68: 16B-aligned rows, 2-way banks
    __shared__ float Denp[4][16];

    // Q A-frags (two d-halves), loaded once
    const float* Qp = Q + ((size_t)(b * LL + q0 + n)) * DD + quad * 8;
    bf16x8 qf0 = cvt8(Qp);        // d = quad*8+j
    bf16x8 qf1 = cvt8(Qp + 32);   // d = 32+quad*8+j

    const float* Kb = K + ((size_t)(b * LL) + n) * DD + quad * 8;
    const float* Vb = V + ((size_t)(b * LL) + quad * 8) * DD + n;
    const int* kmb = kmask + b * LL;

    f32x4 Oacc[4] = {{0,0,0,0},{0,0,0,0},{0,0,0,0},{0,0,0,0}};
    float den[4]  = {0.f, 0.f, 0.f, 0.f};

    float*       pw = &Pl[wave][144 * (n >> 3) + 36 * quad + (n & 7)];
    const float* pr = &Pl[wave][9 * lane];

    const int kbeg = wave * (LL / 4);
    const int kend = kbeg + (LL / 4);

    for (int k0 = kbeg; k0 < kend; k0 += 32) {
        // --- S = Q K^T for a 16q x 32k chunk (two 16-col tiles) ---
        const float* krow = Kb + (size_t)k0 * DD;
        bf16x8 kA0 = cvt8(krow);               // rows k0+n,    d 0..31 slice
        bf16x8 kA1 = cvt8(krow + 32);          //               d 32..63 slice
        bf16x8 kB0 = cvt8(krow + 16 * DD);     // rows k0+16+n
        bf16x8 kB1 = cvt8(krow + 16 * DD + 32);

        f32x4 z = {0.f, 0.f, 0.f, 0.f};
        f32x4 S0 = __builtin_amdgcn_mfma_f32_16x16x32_bf16(qf0, kA0, z, 0, 0, 0);
        S0 = __builtin_amdgcn_mfma_f32_16x16x32_bf16(qf1, kA1, S0, 0, 0, 0);
        f32x4 S1 = __builtin_amdgcn_mfma_f32_16x16x32_bf16(qf0, kB0, z, 0, 0, 0);
        S1 = __builtin_amdgcn_mfma_f32_16x16x32_bf16(qf1, kB1, S1, 0, 0, 0);

        float km0 = (float)kmb[k0 + n];
        float km1 = (float)kmb[k0 + 16 + n];

        // e = exp(s/8)*k_mask ; accumulate den ; scatter P to LDS (A-frag order)
        #pragma unroll
        for (int r = 0; r < 4; ++r) {
            float e0 = __expf(S0[r] * 0.125f) * km0;
            float e1 = __expf(S1[r] * 0.125f) * km1;
            den[r] += e0 + e1;
            pw[9 * r]       = e0;   // k_local = n      (t=0)
            pw[288 + 9 * r] = e1;   // k_local = 16+n   (t=1)
        }

        __builtin_amdgcn_wave_barrier();  // keep reads below the writes

        float pv[8];
        #pragma unroll
        for (int j = 0; j < 8; ++j) pv[j] = pr[j];

        __builtin_amdgcn_wave_barrier();  // keep next-iter writes below reads

        union { bf16x8 v; unsigned u[4]; } pf;
        #pragma unroll
        for (int j = 0; j < 4; ++j)
            pf.u[j] = f2bf_u(pv[2 * j]) | (f2bf_u(pv[2 * j + 1]) << 16);

        // --- O += P V : V B-frags via k-strided fp32 gathers (imm offsets) ---
        const float* vrow = Vb + (size_t)k0 * DD;
        #pragma unroll
        for (int db = 0; db < 4; ++db) {
            union { bf16x8 v; unsigned u[4]; } vf;
            #pragma unroll
            for (int jj = 0; jj < 4; ++jj) {
                unsigned lo = f2bf_u(vrow[(2 * jj) * DD + db * 16]);
                unsigned hi = f2bf_u(vrow[(2 * jj + 1) * DD + db * 16]);
                vf.u[jj] = lo | (hi << 16);
            }
            Oacc[db] = __builtin_amdgcn_mfma_f32_16x16x32_bf16(pf.v, vf.v, Oacc[db], 0, 0, 0);
        }
    }

    // den: sum over the 16 column-lanes within each quad -> den[q=quad*4+r]
    #pragma unroll
    for (int r = 0; r < 4; ++r) {
        float v = den[r];
        v += __shfl_xor(v, 1);
        v += __shfl_xor(v, 2);
        v += __shfl_xor(v, 4);
        v += __shfl_xor(v, 8);
        den[r] = v;
    }

    // dump per-wave partials
    #pragma unroll
    for (int db = 0; db < 4; ++db) {
        #pragma unroll
        for (int r = 0; r < 4; ++r)
            Opart[wave][quad * 4 + r][db * 16 + n] = Oacc[db][r];
    }
    if (n == 0) {
        #pragma unroll
        for (int r = 0; r < 4; ++r) Denp[wave][quad * 4 + r] = den[r];
    }

    __syncthreads();

    // combine 4 k-splits, normalize by max(den,1), apply q_mask, store fp32
    const int q  = tid >> 4;          // 0..15
    const int d0 = (tid & 15) * 4;    // 0..60
    f32x4 sum = *reinterpret_cast<const f32x4*>(&Opart[0][q][d0]);
    sum += *reinterpret_cast<const f32x4*>(&Opart[1][q][d0]);
    sum += *reinterpret_cast<const f32x4*>(&Opart[2][q][d0]);
    sum += *reinterpret_cast<const f32x4*>(&Opart[3][q][d0]);
    float dn  = Denp[0][q] + Denp[1][q] + Denp[2][q] + Denp[3][q];
    float inv = 1.0f / fmaxf(dn, 1.0f);
    int   qm  = qmask[b * LL + q0 + q];
    float s   = qm ? inv : 0.0f;      // masked q-row -> exact 0 (matches ref)
    f32x4 o   = sum * s;

    float* op = Out + ((size_t)(b * LL + q0 + q)) * DD + d0;
    *reinterpret_cast<f32x4*>(op) = o;
}

extern "C" void kernel_launch(void* const* d_in, const int* in_sizes, int n_in,
                              void* d_out, int out_size, void* d_ws, size_t ws_size,
                              hipStream_t stream) {
    (void)in_sizes; (void)n_in; (void)d_ws; (void)ws_size; (void)out_size;
    const float* Q  = (const float*)d_in[0];
    const float* K  = (const float*)d_in[1];
    const float* V  = (const float*)d_in[2];
    const int* qm   = (const int*)d_in[3];
    const int* km   = (const int*)d_in[4];
    float* Out      = (float*)d_out;

    attn_mfma<<<dim3(BB * (LL / 16)), dim3(256), 0, stream>>>(Q, K, V, qm, km, Out);
}

// Round 3
// 136.266 us; speedup vs baseline: 1.0684x; 1.0684x over previous
//
#include <hip/hip_runtime.h>
#include <hip/hip_bf16.h>
#include <stdint.h>

#define BB 8
#define LL 2048
#define DD 64

typedef short bf16x8 __attribute__((ext_vector_type(8)));  // 8 bf16 (4 VGPRs)
typedef float f32x4 __attribute__((ext_vector_type(4)));

// ---- bf16 packing helpers -------------------------------------------------
__device__ __forceinline__ unsigned pk2(float lo, float hi) {
    union { __hip_bfloat162 h; unsigned u; } c;
    c.h = __float22bfloat162_rn(make_float2(lo, hi));   // v_cvt_pk_bf16_f32 on gfx950
    return c.u;
}
__device__ __forceinline__ bf16x8 cvt8f(float4 a, float4 b) {
    union { bf16x8 v; unsigned u[4]; } r;
    r.u[0] = pk2(a.x, a.y); r.u[1] = pk2(a.z, a.w);
    r.u[2] = pk2(b.x, b.y); r.u[3] = pk2(b.z, b.w);
    return r.v;
}
// round-half-up (fallback kernel, proven round 2)
__device__ __forceinline__ unsigned f2bf_u(float f) {
    union { float f; unsigned u; } v; v.f = f;
    return (v.u + 0x8000u) >> 16;
}
__device__ __forceinline__ bf16x8 cvt8(const float* __restrict__ p) {
    float4 a = *reinterpret_cast<const float4*>(p);
    float4 b = *reinterpret_cast<const float4*>(p + 4);
    union { bf16x8 v; unsigned u[4]; } r;
    r.u[0] = f2bf_u(a.x) | (f2bf_u(a.y) << 16);
    r.u[1] = f2bf_u(a.z) | (f2bf_u(a.w) << 16);
    r.u[2] = f2bf_u(b.x) | (f2bf_u(b.y) << 16);
    r.u[3] = f2bf_u(b.z) | (f2bf_u(b.w) << 16);
    return r.v;
}

// ---- V transpose: V[b][k][d] -> VT[b][d][k] (fp32, into d_ws) -------------
__global__ __launch_bounds__(256) void transpose_v(const float* __restrict__ V,
                                                   float* __restrict__ VT) {
    __shared__ float t[64][65];
    const int b  = blockIdx.x >> 5;
    const int kt = (blockIdx.x & 31) << 6;
    {
        const int r  = threadIdx.x >> 2;          // k-local 0..63
        const int cq = (threadIdx.x & 3) << 4;    // d 0..48
        const float* src = V + ((size_t)(b * LL + kt + r)) * DD + cq;
        #pragma unroll
        for (int i = 0; i < 4; ++i) {
            float4 v = *reinterpret_cast<const float4*>(src + 4 * i);
            t[r][cq + 4 * i + 0] = v.x; t[r][cq + 4 * i + 1] = v.y;
            t[r][cq + 4 * i + 2] = v.z; t[r][cq + 4 * i + 3] = v.w;
        }
    }
    __syncthreads();
    {
        const int d  = threadIdx.x >> 2;          // 0..63
        const int kq = (threadIdx.x & 3) << 4;    // k-local 0..48
        float* dst = VT + ((size_t)(b * DD + d)) * LL + kt + kq;
        #pragma unroll
        for (int u = 0; u < 4; ++u) {
            float4 v = { t[kq + 4 * u + 0][d], t[kq + 4 * u + 1][d],
                         t[kq + 4 * u + 2][d], t[kq + 4 * u + 3][d] };
            *reinterpret_cast<float4*>(dst + 4 * u) = v;
        }
    }
}

// ---- main attention kernel ------------------------------------------------
// Block: 4 waves, each QW=32 queries (2 subtiles of 16), k-split 4 (512 k each).
// Grid: 8 b x 64 q-tiles = 512 blocks (2 blocks/CU, 8 waves/CU).
// S^T = K·Q^T (A=K, B=Q): C holds P^T[k=quad*4+r][q=ln] -> cross-quad shuffles
// convert to the PV A-fragment. V^T rows give contiguous-k B-frags (dwordx4).
struct ChunkRegs { float4 kr[8]; float4 vr[8]; int4 mr[2]; };

__device__ __forceinline__ void load_chunk(const float* __restrict__ Kb,
                                           const float* __restrict__ Vb,
                                           const int* __restrict__ kmb,
                                           int k0, int quad, ChunkRegs& c) {
    const float* kp = Kb + (size_t)k0 * DD;
    #pragma unroll
    for (int t = 0; t < 2; ++t) {
        c.kr[t * 4 + 0] = *reinterpret_cast<const float4*>(kp + t * 16 * DD);
        c.kr[t * 4 + 1] = *reinterpret_cast<const float4*>(kp + t * 16 * DD + 4);
        c.kr[t * 4 + 2] = *reinterpret_cast<const float4*>(kp + t * 16 * DD + 32);
        c.kr[t * 4 + 3] = *reinterpret_cast<const float4*>(kp + t * 16 * DD + 36);
    }
    const float* vp = Vb + k0 + 8 * quad;
    #pragma unroll
    for (int db = 0; db < 4; ++db) {
        c.vr[db * 2 + 0] = *reinterpret_cast<const float4*>(vp + db * 16 * LL);
        c.vr[db * 2 + 1] = *reinterpret_cast<const float4*>(vp + db * 16 * LL + 4);
    }
    c.mr[0] = *reinterpret_cast<const int4*>(kmb + k0 + 4 * quad);
    c.mr[1] = *reinterpret_cast<const int4*>(kmb + k0 + 16 + 4 * quad);
}

__global__ __launch_bounds__(256, 2) void attn2(
    const float* __restrict__ Q,
    const float* __restrict__ K,
    const float* __restrict__ VT,
    const int* __restrict__ qmask,
    const int* __restrict__ kmask,
    float* __restrict__ Out)
{
    const int tid  = threadIdx.x;
    const int wave = tid >> 6;
    const int lane = tid & 63;
    const int ln   = lane & 15;
    const int quad = lane >> 4;

    const int bx = blockIdx.x;
    const int b  = bx >> 6;            // 8 batches
    const int q0 = (bx & 63) << 5;     // 32 queries per block

    __shared__ float Opart[4][32][68];
    __shared__ float Denp[4][2][16];

    // Q B-frags: qf[sub][half], q = q0+16*sub+ln, d = half*32 + quad*8 + j
    bf16x8 qf[2][2];
    #pragma unroll
    for (int s = 0; s < 2; ++s) {
        const float* qp = Q + ((size_t)(b * LL + q0 + 16 * s + ln)) * DD + quad * 8;
        qf[s][0] = cvt8f(*reinterpret_cast<const float4*>(qp),
                         *reinterpret_cast<const float4*>(qp + 4));
        qf[s][1] = cvt8f(*reinterpret_cast<const float4*>(qp + 32),
                         *reinterpret_cast<const float4*>(qp + 36));
    }

    const float* Kb  = K + ((size_t)(b * LL) + ln) * DD + quad * 8;
    const float* Vb  = VT + ((size_t)(b * DD) + ln) * LL;   // + db*16*LL + k0 + 8*quad
    const int*   kmb = kmask + b * LL;

    const int kbeg = wave * (LL / 4);
    const int kend = kbeg + (LL / 4);

    f32x4 Oacc[2][4];
    #pragma unroll
    for (int s = 0; s < 2; ++s)
        #pragma unroll
        for (int d = 0; d < 4; ++d) Oacc[s][d] = (f32x4){0.f, 0.f, 0.f, 0.f};
    float dsum[2] = {0.f, 0.f};

    const int src0 = ln + ((quad & 1) << 5);   // lane of source quad 2*(quad&1)
    const int src1 = src0 + 16;
    const bool hi  = quad >= 2;                // tile select after shuffle

    ChunkRegs cur, nxt;
    load_chunk(Kb, Vb, kmb, kbeg, quad, cur);

    #pragma unroll 4
    for (int k0 = kbeg; k0 < kend; k0 += 32) {
        const int k1 = (k0 + 32 < kend) ? (k0 + 32) : kbeg;   // harmless wrap
        load_chunk(Kb, Vb, kmb, k1, quad, nxt);

        // K A-frags
        bf16x8 kA[2][2];
        #pragma unroll
        for (int t = 0; t < 2; ++t) {
            kA[t][0] = cvt8f(cur.kr[t * 4 + 0], cur.kr[t * 4 + 1]);
            kA[t][1] = cvt8f(cur.kr[t * 4 + 2], cur.kr[t * 4 + 3]);
        }
        // V B-frags
        bf16x8 vf[4];
        #pragma unroll
        for (int db = 0; db < 4; ++db)
            vf[db] = cvt8f(cur.vr[db * 2], cur.vr[db * 2 + 1]);

        #pragma unroll
        for (int s = 0; s < 2; ++s) {
            // S^T tiles: lane holds P^T[k_local=16t+4quad+r][q=ln]
            unsigned w[2][2];
            #pragma unroll
            for (int t = 0; t < 2; ++t) {
                f32x4 acc = (f32x4){0.f, 0.f, 0.f, 0.f};
                acc = __builtin_amdgcn_mfma_f32_16x16x32_bf16(kA[t][0], qf[s][0], acc, 0, 0, 0);
                acc = __builtin_amdgcn_mfma_f32_16x16x32_bf16(kA[t][1], qf[s][1], acc, 0, 0, 0);
                float e0 = __expf(acc[0] * 0.125f) * (float)cur.mr[t].x;
                float e1 = __expf(acc[1] * 0.125f) * (float)cur.mr[t].y;
                float e2 = __expf(acc[2] * 0.125f) * (float)cur.mr[t].z;
                float e3 = __expf(acc[3] * 0.125f) * (float)cur.mr[t].w;
                dsum[s] += (e0 + e1) + (e2 + e3);
                w[t][0] = pk2(e0, e1);
                w[t][1] = pk2(e2, e3);
            }
            // P^T(C-layout) -> P(A-layout): pure cross-quad permutation at fixed q
            union { bf16x8 v; unsigned u[4]; } pf;
            {
                unsigned a0 = __shfl(w[0][0], src0), b0 = __shfl(w[1][0], src0);
                unsigned a1 = __shfl(w[0][1], src0), b1 = __shfl(w[1][1], src0);
                unsigned a2 = __shfl(w[0][0], src1), b2 = __shfl(w[1][0], src1);
                unsigned a3 = __shfl(w[0][1], src1), b3 = __shfl(w[1][1], src1);
                pf.u[0] = hi ? b0 : a0;
                pf.u[1] = hi ? b1 : a1;
                pf.u[2] = hi ? b2 : a2;
                pf.u[3] = hi ? b3 : a3;
            }
            #pragma unroll
            for (int db = 0; db < 4; ++db)
                Oacc[s][db] = __builtin_amdgcn_mfma_f32_16x16x32_bf16(pf.v, vf[db], Oacc[s][db], 0, 0, 0);
        }

        cur = nxt;
    }

    // den: reduce across quads (q index = ln)
    #pragma unroll
    for (int s = 0; s < 2; ++s) {
        float v = dsum[s];
        v += __shfl_xor(v, 16);
        v += __shfl_xor(v, 32);
        dsum[s] = v;
    }

    // dump per-wave partials: O rows are q_sub = quad*4+r, cols d = 16*db+ln
    #pragma unroll
    for (int s = 0; s < 2; ++s)
        #pragma unroll
        for (int db = 0; db < 4; ++db)
            #pragma unroll
            for (int r = 0; r < 4; ++r)
                Opart[wave][s * 16 + quad * 4 + r][db * 16 + ln] = Oacc[s][db][r];
    if (quad == 0) {
        Denp[wave][0][ln] = dsum[0];
        Denp[wave][1][ln] = dsum[1];
    }
    __syncthreads();

    // combine 4 k-splits, normalize by max(den,1), apply q_mask, store fp32
    const int q  = tid >> 3;           // 0..31
    const int d0 = (tid & 7) << 3;     // 0..56
    f32x4 s0 = (f32x4){0.f, 0.f, 0.f, 0.f}, s1 = s0;
    #pragma unroll
    for (int w = 0; w < 4; ++w) {
        s0 += *reinterpret_cast<const f32x4*>(&Opart[w][q][d0]);
        s1 += *reinterpret_cast<const f32x4*>(&Opart[w][q][d0 + 4]);
    }
    float dn = Denp[0][q >> 4][q & 15] + Denp[1][q >> 4][q & 15]
             + Denp[2][q >> 4][q & 15] + Denp[3][q >> 4][q & 15];
    float inv = 1.0f / fmaxf(dn, 1.0f);
    float sc  = qmask[b * LL + q0 + q] ? inv : 0.0f;
    s0 *= sc; s1 *= sc;
    float* op = Out + ((size_t)(b * LL + q0 + q)) * DD + d0;
    *reinterpret_cast<f32x4*>(op)     = s0;
    *reinterpret_cast<f32x4*>(op + 4) = s1;
}

// ---- fallback (round-2 kernel, used only if ws too small) -----------------
__global__ __launch_bounds__(256, 4) void attn_mfma(
    const float* __restrict__ Q, const float* __restrict__ K,
    const float* __restrict__ V, const int* __restrict__ qmask,
    const int* __restrict__ kmask, float* __restrict__ Out)
{
    const int tid  = threadIdx.x;
    const int wave = tid >> 6;
    const int lane = tid & 63;
    const int n    = lane & 15;
    const int quad = lane >> 4;
    const int bx = blockIdx.x;
    const int b  = bx >> 7;
    const int q0 = (bx & 127) << 4;
    __shared__ float Pl[4][576];
    __shared__ float Opart[4][16][68];
    __shared__ float Denp[4][16];
    const float* Qp = Q + ((size_t)(b * LL + q0 + n)) * DD + quad * 8;
    bf16x8 qf0 = cvt8(Qp);
    bf16x8 qf1 = cvt8(Qp + 32);
    const float* Kb = K + ((size_t)(b * LL) + n) * DD + quad * 8;
    const float* Vb = V + ((size_t)(b * LL) + quad * 8) * DD + n;
    const int* kmb = kmask + b * LL;
    f32x4 Oacc[4] = {{0,0,0,0},{0,0,0,0},{0,0,0,0},{0,0,0,0}};
    float den[4]  = {0.f, 0.f, 0.f, 0.f};
    float*       pw = &Pl[wave][144 * (n >> 3) + 36 * quad + (n & 7)];
    const float* pr = &Pl[wave][9 * lane];
    const int kbeg = wave * (LL / 4);
    const int kend = kbeg + (LL / 4);
    for (int k0 = kbeg; k0 < kend; k0 += 32) {
        const float* krow = Kb + (size_t)k0 * DD;
        bf16x8 kA0 = cvt8(krow);
        bf16x8 kA1 = cvt8(krow + 32);
        bf16x8 kB0 = cvt8(krow + 16 * DD);
        bf16x8 kB1 = cvt8(krow + 16 * DD + 32);
        f32x4 z = {0.f, 0.f, 0.f, 0.f};
        f32x4 S0 = __builtin_amdgcn_mfma_f32_16x16x32_bf16(qf0, kA0, z, 0, 0, 0);
        S0 = __builtin_amdgcn_mfma_f32_16x16x32_bf16(qf1, kA1, S0, 0, 0, 0);
        f32x4 S1 = __builtin_amdgcn_mfma_f32_16x16x32_bf16(qf0, kB0, z, 0, 0, 0);
        S1 = __builtin_amdgcn_mfma_f32_16x16x32_bf16(qf1, kB1, S1, 0, 0, 0);
        float km0 = (float)kmb[k0 + n];
        float km1 = (float)kmb[k0 + 16 + n];
        #pragma unroll
        for (int r = 0; r < 4; ++r) {
            float e0 = __expf(S0[r] * 0.125f) * km0;
            float e1 = __expf(S1[r] * 0.125f) * km1;
            den[r] += e0 + e1;
            pw[9 * r]       = e0;
            pw[288 + 9 * r] = e1;
        }
        __builtin_amdgcn_wave_barrier();
        float pv[8];
        #pragma unroll
        for (int j = 0; j < 8; ++j) pv[j] = pr[j];
        __builtin_amdgcn_wave_barrier();
        union { bf16x8 v; unsigned u[4]; } pf;
        #pragma unroll
        for (int j = 0; j < 4; ++j)
            pf.u[j] = f2bf_u(pv[2 * j]) | (f2bf_u(pv[2 * j + 1]) << 16);
        const float* vrow = Vb + (size_t)k0 * DD;
        #pragma unroll
        for (int db = 0; db < 4; ++db) {
            union { bf16x8 v; unsigned u[4]; } vfr;
            #pragma unroll
            for (int jj = 0; jj < 4; ++jj) {
                unsigned lo = f2bf_u(vrow[(2 * jj) * DD + db * 16]);
                unsigned hi2 = f2bf_u(vrow[(2 * jj + 1) * DD + db * 16]);
                vfr.u[jj] = lo | (hi2 << 16);
            }
            Oacc[db] = __builtin_amdgcn_mfma_f32_16x16x32_bf16(pf.v, vfr.v, Oacc[db], 0, 0, 0);
        }
    }
    #pragma unroll
    for (int r = 0; r < 4; ++r) {
        float v = den[r];
        v += __shfl_xor(v, 1); v += __shfl_xor(v, 2);
        v += __shfl_xor(v, 4); v += __shfl_xor(v, 8);
        den[r] = v;
    }
    #pragma unroll
    for (int db = 0; db < 4; ++db)
        #pragma unroll
        for (int r = 0; r < 4; ++r)
            Opart[wave][quad * 4 + r][db * 16 + n] = Oacc[db][r];
    if (n == 0) {
        #pragma unroll
        for (int r = 0; r < 4; ++r) Denp[wave][quad * 4 + r] = den[r];
    }
    __syncthreads();
    const int q  = tid >> 4;
    const int d0 = (tid & 15) * 4;
    f32x4 sum = *reinterpret_cast<const f32x4*>(&Opart[0][q][d0]);
    sum += *reinterpret_cast<const f32x4*>(&Opart[1][q][d0]);
    sum += *reinterpret_cast<const f32x4*>(&Opart[2][q][d0]);
    sum += *reinterpret_cast<const f32x4*>(&Opart[3][q][d0]);
    float dn  = Denp[0][q] + Denp[1][q] + Denp[2][q] + Denp[3][q];
    float inv = 1.0f / fmaxf(dn, 1.0f);
    float s   = qmask[b * LL + q0 + q] ? inv : 0.0f;
    f32x4 o   = sum * s;
    float* op = Out + ((size_t)(b * LL + q0 + q)) * DD + d0;
    *reinterpret_cast<f32x4*>(op) = o;
}

extern "C" void kernel_launch(void* const* d_in, const int* in_sizes, int n_in,
                              void* d_out, int out_size, void* d_ws, size_t ws_size,
                              hipStream_t stream) {
    (void)in_sizes; (void)n_in; (void)out_size;
    const float* Q  = (const float*)d_in[0];
    const float* K  = (const float*)d_in[1];
    const float* V  = (const float*)d_in[2];
    const int* qm   = (const int*)d_in[3];
    const int* km   = (const int*)d_in[4];
    float* Out      = (float*)d_out;

    const size_t vt_bytes = (size_t)BB * LL * DD * sizeof(float);  // 4 MiB
    if (ws_size >= vt_bytes && d_ws != nullptr) {
        float* VT = (float*)d_ws;
        transpose_v<<<dim3(BB * (LL / 64)), dim3(256), 0, stream>>>(V, VT);
        attn2<<<dim3(BB * (LL / 32)), dim3(256), 0, stream>>>(Q, K, VT, qm, km, Out);
    } else {
        attn_mfma<<<dim3(BB * (LL / 16)), dim3(256), 0, stream>>>(Q, K, V, qm, km, Out);
    }
}